// Round 5
// baseline (142.512 us; speedup 1.0000x reference)
//
#include <hip/hip_runtime.h>
#include <cmath>

// DotMaskLayer: B=16384, D=256, H=64, M=128.
// keep(j) = (j < K) | (128 <= j < 128+K)  [j=256 bias iff K>128; K<=128 in data]
// out[b,h] = tanh( sum_j keep(j)*Y[b,j]*W[b,j,h] ),  W = AUX.reshape(B,257,64)
// Y[b,j] = X[b,j] for j<256, Y[b,256] = 1.
//
// R5: ONE WAVE PER BATCH ROW (64-thread blocks). Removes R4's two residual
// costs: (a) ~11% chunk-quantization inflation from splitting ceil(k/4) chunks
// over 4 waves, (b) per-b LDS+barrier+cross-wave-reduce epilogue. Work
// retirement is wave-granular and HW dispatch is work-conserving.
//
// Lane layout: jo = lane>>4 (row within 4-row chunk), h4 = (lane&15)*4.
// Per iteration the wave loads chunk pair {j0..j0+3, 128+j0..128+j0+3}:
// two independent 1KB contiguous dwordx4 wave-loads (2KB in flight).

#define D_DIM 256
#define H_DIM 64
#define ROWS 257
#define ROWSTRIDE (ROWS * H_DIM)   // 16448 floats per batch row of AUX

__global__ __launch_bounds__(64)
void dotmask_kernel(const float* __restrict__ X,
                    const float* __restrict__ AUX,
                    const int* __restrict__ K,
                    float* __restrict__ out)
{
    const int b    = blockIdx.x;
    const int lane = threadIdx.x;       // 0..63
    const int jo   = lane >> 4;         // row offset within chunk (0..3)
    const int h4   = (lane & 15) * 4;   // this lane's 4 consecutive h's

    const int k = K[b];
    const float* __restrict__ Wb = AUX + (size_t)b * ROWSTRIDE;
    const float* __restrict__ Xb = X   + (size_t)b * D_DIM;

    float ax = 0.f, ay = 0.f, az = 0.f, aw = 0.f;

    // j0 steps over side-1 chunks; each iteration also covers the mirrored
    // side-2 chunk at j0+128. Max j = k-1+3 <= 130; j+128 <= 258 -> clamp
    // (clamped lanes are mask-zeroed; clamp keeps loads in-bounds at b=B-1).
    for (int j0 = 0; j0 < k; j0 += 4) {
        const int j   = j0 + jo;
        const int j2  = j + 128;
        const int j2c = (j2 > 256) ? 256 : j2;

        const float4 w1 = *reinterpret_cast<const float4*>(Wb + (size_t)j   * H_DIM + h4);
        const float4 w2 = *reinterpret_cast<const float4*>(Wb + (size_t)j2c * H_DIM + h4);
        const float x1r = Xb[j];                          // j <= 130 < 256
        const float x2r = Xb[(j2c > 255) ? 255 : j2c];

        const bool  m  = (j < k);
        const float x1 = m ? x1r : 0.f;
        const float x2 = m ? x2r : 0.f;

        ax += x1 * w1.x; ay += x1 * w1.y; az += x1 * w1.z; aw += x1 * w1.w;
        ax += x2 * w2.x; ay += x2 * w2.y; az += x2 * w2.z; aw += x2 * w2.w;
    }

    // bias row j=256 (kept iff k > 128; never with this data, kept for generality)
    if (k > 128 && jo == 0) {
        const float4 wv = *reinterpret_cast<const float4*>(Wb + (size_t)256 * H_DIM + h4);
        ax += wv.x; ay += wv.y; az += wv.z; aw += wv.w;
    }

    // reduce across the 4 jo-groups (lanes l, l+16, l+32, l+48 share h4)
    ax += __shfl_xor(ax, 16); ay += __shfl_xor(ay, 16);
    az += __shfl_xor(az, 16); aw += __shfl_xor(aw, 16);
    ax += __shfl_xor(ax, 32); ay += __shfl_xor(ay, 32);
    az += __shfl_xor(az, 32); aw += __shfl_xor(aw, 32);

    if (lane < 16) {
        float4 r;
        r.x = tanhf(ax); r.y = tanhf(ay); r.z = tanhf(az); r.w = tanhf(aw);
        *reinterpret_cast<float4*>(out + (size_t)b * H_DIM + h4) = r;
    }
}

extern "C" void kernel_launch(void* const* d_in, const int* in_sizes, int n_in,
                              void* d_out, int out_size, void* d_ws, size_t ws_size,
                              hipStream_t stream)
{
    const float* X   = (const float*)d_in[0];
    const float* AUX = (const float*)d_in[1];
    const int*   K   = (const int*)d_in[2];
    float* out = (float*)d_out;

    const int B = in_sizes[2];                 // 16384
    dotmask_kernel<<<B, 64, 0, stream>>>(X, AUX, K, out);
}

// Round 6
// 126.192 us; speedup vs baseline: 1.1293x; 1.1293x over previous
//
#include <hip/hip_runtime.h>
#include <cmath>

// DotMaskLayer: B=16384, D=256, H=64, M=128.
// keep(j) = (j < K) | (128 <= j < 128+K)  [j=256 bias iff K>128; K<=128 in data]
// out[b,h] = tanh( sum_j keep(j)*Y[b,j]*W[b,j,h] ),  W = AUX.reshape(B,257,64)
// Y[b,j] = X[b,j] for j<256, Y[b,256] = 1.
//
// R6: ONE ROW PER 128-THREAD BLOCK (2-wave split-K).
//  - R4 (256t, 4-wave split) = 116us: block time ~ single k (good) but chunk
//    quantization ceil(ceil(k/4)/4) inflates ~11%.
//  - R5 (64t, 1 wave/row) = 142us: WG-slot cap (~16 WG/CU) halves occupancy.
//  - R6: 128t keeps 32 waves/CU (16 WG x 2 waves), quantization drops to
//    ~3.5% (ceil(C/2), C=ceil(k/4)), epilogue halves.
//
// Lane layout: jo = lane>>4 (row in 4-row chunk), h4 = (lane&15)*4.
// Wave w owns chunks w, w+2, w+4, ... (round-robin -> adjacent streaming);
// each chunk covers rows [j0, j0+4) and mirrored [128+j0, 128+j0+4):
// two independent 1KB contiguous dwordx4 wave-loads per iteration.

#define D_DIM 256
#define H_DIM 64
#define ROWS 257
#define ROWSTRIDE (ROWS * H_DIM)   // 16448 floats per batch row of AUX

__global__ __launch_bounds__(128, 8)
void dotmask_kernel(const float* __restrict__ X,
                    const float* __restrict__ AUX,
                    const int* __restrict__ K,
                    float* __restrict__ out)
{
    const int b    = blockIdx.x;
    const int tid  = threadIdx.x;
    const int lane = tid & 63;
    const int w    = tid >> 6;          // wave id 0..1 (both share row b)
    const int jo   = lane >> 4;         // row offset within chunk (0..3)
    const int h4   = (lane & 15) * 4;   // this lane's 4 consecutive h's

    const int k = K[b];
    const float* __restrict__ Wb = AUX + (size_t)b * ROWSTRIDE;
    const float* __restrict__ Xb = X   + (size_t)b * D_DIM;

    float ax = 0.f, ay = 0.f, az = 0.f, aw = 0.f;

    // Wave w owns 4-row chunks j0 = 4*(w + 2t); each also covers j0+128.
    // Max j = k-1+3 <= 130 (in-bounds); j+128 <= 258 -> clamp (mask-zeroed).
    for (int j0 = w * 4; j0 < k; j0 += 8) {
        const int j   = j0 + jo;
        const int j2  = j + 128;
        const int j2c = (j2 > 256) ? 256 : j2;

        const float4 w1 = *reinterpret_cast<const float4*>(Wb + (size_t)j   * H_DIM + h4);
        const float4 w2 = *reinterpret_cast<const float4*>(Wb + (size_t)j2c * H_DIM + h4);
        const float x1r = Xb[j];                          // j <= 130 < 256
        const float x2r = Xb[(j2c > 255) ? 255 : j2c];

        const bool  m  = (j < k);
        const float x1 = m ? x1r : 0.f;
        const float x2 = m ? x2r : 0.f;

        ax += x1 * w1.x; ay += x1 * w1.y; az += x1 * w1.z; aw += x1 * w1.w;
        ax += x2 * w2.x; ay += x2 * w2.y; az += x2 * w2.z; aw += x2 * w2.w;
    }

    // bias row j=256 (kept iff k > 128; never with this data, kept for generality)
    if (k > 128 && w == 0 && jo == 0) {
        const float4 wv = *reinterpret_cast<const float4*>(Wb + (size_t)256 * H_DIM + h4);
        ax += wv.x; ay += wv.y; az += wv.z; aw += wv.w;
    }

    // reduce across the 4 jo-groups (lanes l, l+16, l+32, l+48 share h4)
    ax += __shfl_xor(ax, 16); ay += __shfl_xor(ay, 16);
    az += __shfl_xor(az, 16); aw += __shfl_xor(aw, 16);
    ax += __shfl_xor(ax, 32); ay += __shfl_xor(ay, 32);
    az += __shfl_xor(az, 32); aw += __shfl_xor(aw, 32);

    // combine the 2 waves' partials via LDS
    __shared__ float lds[2][H_DIM];
    if (lane < 16) {
        float4 p; p.x = ax; p.y = ay; p.z = az; p.w = aw;
        *reinterpret_cast<float4*>(&lds[w][h4]) = p;
    }
    __syncthreads();

    if (tid < H_DIM) {
        const float s = lds[0][tid] + lds[1][tid];
        out[(size_t)b * H_DIM + tid] = tanhf(s);
    }
}

extern "C" void kernel_launch(void* const* d_in, const int* in_sizes, int n_in,
                              void* d_out, int out_size, void* d_ws, size_t ws_size,
                              hipStream_t stream)
{
    const float* X   = (const float*)d_in[0];
    const float* AUX = (const float*)d_in[1];
    const int*   K   = (const int*)d_in[2];
    float* out = (float*)d_out;

    const int B = in_sizes[2];                 // 16384
    dotmask_kernel<<<B, 128, 0, stream>>>(X, AUX, K, out);
}

// Round 7
// 114.179 us; speedup vs baseline: 1.2481x; 1.1052x over previous
//
#include <hip/hip_runtime.h>
#include <cmath>

// DotMaskLayer: B=16384, D=256, H=64, M=128.
// keep(j) = (j < K) | (128 <= j < 128+K)  [j=256 bias iff K>128; K<=128 in data]
// out[b,h] = tanh( sum_j keep(j)*Y[b,j]*W[b,j,h] ),  W = AUX.reshape(B,257,64)
// Y[b,j] = X[b,j] for j<256, Y[b,256] = 1.
//
// R7: R4 structure (one 256-thread block per b, 4-wave round-robin split-K,
// 4-row chunks) + 2-chunk-per-iteration unroll. Each wave issues 4 independent
// 1KB loads back-to-back; the 4 near-lockstep waves of a block then have a
// ~8KB-contiguous-per-side in-flight window (R4 was ~4KB; R6's 2KB and
// R5/R1's 1KB were progressively slower -> request-grouping theory).
// Second chunk is wave-uniform-guarded so no extra HBM traffic.

#define D_DIM 256
#define H_DIM 64
#define ROWS 257
#define ROWSTRIDE (ROWS * H_DIM)   // 16448 floats per batch row of AUX

__global__ __launch_bounds__(256, 8)
void dotmask_kernel(const float* __restrict__ X,
                    const float* __restrict__ AUX,
                    const int* __restrict__ K,
                    float* __restrict__ out)
{
    const int b    = blockIdx.x;
    const int tid  = threadIdx.x;
    const int lane = tid & 63;
    const int w    = tid >> 6;          // wave id 0..3 (all share row b)
    const int jo   = lane >> 4;         // row offset within 4-row chunk
    const int h4   = (lane & 15) * 4;   // this lane's 4 consecutive h's

    const int k = K[b];
    const float* __restrict__ Wb  = AUX + (size_t)b * ROWSTRIDE;
    const float* __restrict__ WbH = Wb + h4;
    const float* __restrict__ Xb  = X   + (size_t)b * D_DIM;

    float ax = 0.f, ay = 0.f, az = 0.f, aw = 0.f;

    // Wave w owns 4-row chunks c = w, w+4, w+8, ... (round-robin).
    // Unrolled x2: body handles chunk A (j0) and chunk B (j0+16).
    // Row indices: side-1 j <= 146 < 257 (in-bounds); side-2 j+128 clamped to
    // 256 (clamped lanes are mask-zeroed; mask for side-2 is the SAME (j<k)).
    for (int j0 = w * 4; j0 < k; j0 += 32) {
        // ---- chunk A loads ----
        const int ja   = j0 + jo;
        const int ja2  = (ja + 128 > 256) ? 256 : (ja + 128);
        const float4 wa1 = *reinterpret_cast<const float4*>(WbH + ((size_t)ja  << 6));
        const float4 wa2 = *reinterpret_cast<const float4*>(WbH + ((size_t)ja2 << 6));
        const float  xa1r = Xb[ja];
        const float  xa2r = Xb[(ja + 128 > 255) ? 255 : (ja + 128)];

        // ---- chunk B loads (wave-uniform guard: no wasted fetch) ----
        const int j0b = j0 + 16;
        const bool doB = (j0b < k);
        float4 wb1 = make_float4(0,0,0,0), wb2 = make_float4(0,0,0,0);
        float  xb1r = 0.f, xb2r = 0.f;
        int jb = 0;
        if (doB) {
            jb = j0b + jo;
            const int jb2 = (jb + 128 > 256) ? 256 : (jb + 128);
            wb1 = *reinterpret_cast<const float4*>(WbH + ((size_t)jb  << 6));
            wb2 = *reinterpret_cast<const float4*>(WbH + ((size_t)jb2 << 6));
            xb1r = Xb[jb];
            xb2r = Xb[(jb + 128 > 255) ? 255 : (jb + 128)];
        }

        // ---- FMAs (after all loads issued) ----
        const float xa1 = (ja < k) ? xa1r : 0.f;
        const float xa2 = (ja < k) ? xa2r : 0.f;
        ax += xa1 * wa1.x; ay += xa1 * wa1.y; az += xa1 * wa1.z; aw += xa1 * wa1.w;
        ax += xa2 * wa2.x; ay += xa2 * wa2.y; az += xa2 * wa2.z; aw += xa2 * wa2.w;

        const float xb1 = (doB && jb < k) ? xb1r : 0.f;
        const float xb2 = (doB && jb < k) ? xb2r : 0.f;
        ax += xb1 * wb1.x; ay += xb1 * wb1.y; az += xb1 * wb1.z; aw += xb1 * wb1.w;
        ax += xb2 * wb2.x; ay += xb2 * wb2.y; az += xb2 * wb2.z; aw += xb2 * wb2.w;
    }

    // bias row j=256 (kept iff k > 128; never with this data, kept for generality)
    if (k > 128 && w == 0 && jo == 0) {
        const float4 wv = *reinterpret_cast<const float4*>(Wb + (size_t)256 * H_DIM + h4);
        ax += wv.x; ay += wv.y; az += wv.z; aw += wv.w;
    }

    // reduce across the 4 jo-groups (lanes l, l+16, l+32, l+48 share h4)
    ax += __shfl_xor(ax, 16); ay += __shfl_xor(ay, 16);
    az += __shfl_xor(az, 16); aw += __shfl_xor(aw, 16);
    ax += __shfl_xor(ax, 32); ay += __shfl_xor(ay, 32);
    az += __shfl_xor(az, 32); aw += __shfl_xor(aw, 32);

    // combine the 4 waves' partials via LDS
    __shared__ float lds[4][H_DIM];
    if (lane < 16) {
        float4 p; p.x = ax; p.y = ay; p.z = az; p.w = aw;
        *reinterpret_cast<float4*>(&lds[w][h4]) = p;
    }
    __syncthreads();

    if (tid < H_DIM) {
        const float s = lds[0][tid] + lds[1][tid] + lds[2][tid] + lds[3][tid];
        out[(size_t)b * H_DIM + tid] = tanhf(s);
    }
}

extern "C" void kernel_launch(void* const* d_in, const int* in_sizes, int n_in,
                              void* d_out, int out_size, void* d_ws, size_t ws_size,
                              hipStream_t stream)
{
    const float* X   = (const float*)d_in[0];
    const float* AUX = (const float*)d_in[1];
    const int*   K   = (const int*)d_in[2];
    float* out = (float*)d_out;

    const int B = in_sizes[2];                 // 16384
    dotmask_kernel<<<B, 256, 0, stream>>>(X, AUX, K, out);
}